// Round 1
// baseline (588.248 us; speedup 1.0000x reference)
//
#include <hip/hip_runtime.h>
#include <hip/hip_bf16.h>
#include <stdint.h>

#define TB 8
#define TC 256
#define TH 120
#define TW 120
#define THW 14400
#define TOC 256
#define PH 122
#define PW 122

typedef short bf16x8 __attribute__((ext_vector_type(8)));
typedef float f32x4 __attribute__((ext_vector_type(4)));

// ---- workspace layout (bytes) ----
#define OUTP_BYTES ((size_t)TB * PH * PW * TC * 2)          // 60,964,864  padded channel-last bf16 intermediate
#define YP_OFF     OUTP_BYTES
#define DK_OFF     (YP_OFF + (size_t)TB * TC * 9 * 4)
#define WP_OFF     (DK_OFF + (size_t)TB * TC * 9 * 4)

__global__ void zero_kernel(uint4* __restrict__ p, int n) {
    int i = blockIdx.x * blockDim.x + threadIdx.x;
    uint4 z; z.x = 0u; z.y = 0u; z.z = 0u; z.w = 0u;
    for (; i < n; i += gridDim.x * blockDim.x) p[i] = z;
}

// yp[b][c][ij] = mean of 40x40 block (ij = bh*3+bw)
__global__ void pool_kernel(const float* __restrict__ y, float* __restrict__ yp) {
    int bc = blockIdx.x;                     // b*256 + c
    const float* src = y + (size_t)bc * THW;
    int t = threadIdx.x;
    float acc[9];
    #pragma unroll
    for (int bin = 0; bin < 9; ++bin) {
        int bh = (bin / 3) * 40, bw = (bin % 3) * 40;
        float a = 0.f;
        for (int i = t; i < 1600; i += 256) {
            int r = i / 40;
            int cw = i - r * 40;
            a += src[(bh + r) * TW + bw + cw];
        }
        acc[bin] = a;
    }
    __shared__ float red[256][9];
    #pragma unroll
    for (int j = 0; j < 9; ++j) red[t][j] = acc[j];
    __syncthreads();
    for (int st = 128; st > 0; st >>= 1) {
        if (t < st) {
            #pragma unroll
            for (int j = 0; j < 9; ++j) red[t][j] += red[t + st][j];
        }
        __syncthreads();
    }
    if (t < 9) yp[bc * 9 + t] = red[0][t] * (1.f / 1600.f);
}

// dk[b][oc][ij] = gen_b[oc] + sum_c gen_w[oc][c] * yp[b][c][ij]
__global__ void gen_kernel(const float* __restrict__ yp, const float* __restrict__ gen_w,
                           const float* __restrict__ gen_b, float* __restrict__ dk) {
    int b = blockIdx.x, t = threadIdx.x;     // t = oc
    __shared__ float yps[TC * 9];
    for (int i = t; i < TC * 9; i += 256) yps[i] = yp[b * TC * 9 + i];
    __syncthreads();
    float acc[9];
    float bias = gen_b[t];
    #pragma unroll
    for (int j = 0; j < 9; ++j) acc[j] = bias;
    for (int c = 0; c < TC; ++c) {
        float w = gen_w[t * TC + c];
        #pragma unroll
        for (int j = 0; j < 9; ++j) acc[j] += w * yps[c * 9 + j];
    }
    #pragma unroll
    for (int j = 0; j < 9; ++j) dk[(b * TC + t) * 9 + j] = acc[j];
}

// depthwise dynamic 3x3 (pad 1, cross-correlation), writes channel-last padded bf16:
// outP[b][h+1][w+1][c]
__global__ __launch_bounds__(1024) void dw_kernel(const float* __restrict__ x,
        const float* __restrict__ dk, __hip_bfloat16* __restrict__ outP) {
    int bid = blockIdx.x;
    int b = bid / TH;
    int h = bid - b * TH;
    int t = threadIdx.x;
    __shared__ float dks[TC * 9];
    __shared__ __align__(16) __hip_bfloat16 stage[TW][40];   // 40 pad keeps 16B-aligned rows
    for (int i = t; i < TC * 9; i += 1024) dks[i] = dk[b * TC * 9 + i];
    __syncthreads();
    const float* xb = x + (size_t)b * TC * THW;
    for (int cc = 0; cc < 8; ++cc) {
        int cbase = cc * 32;
        for (int idx = t; idx < 3840; idx += 1024) {
            int c = idx / TW;
            int w = idx - c * TW;
            const float* xp = xb + (size_t)(cbase + c) * THW;
            const float* dkp = &dks[(cbase + c) * 9];
            float a = 0.f;
            #pragma unroll
            for (int di = 0; di < 3; ++di) {
                int hh = h + di - 1;                 // uniform across block
                if (hh >= 0 && hh < TH) {
                    const float* row = xp + hh * TW;
                    #pragma unroll
                    for (int dj = 0; dj < 3; ++dj) {
                        int ww = w + dj - 1;
                        float xv = (ww >= 0 && ww < TW) ? row[ww] : 0.f;
                        a += xv * dkp[di * 3 + dj];
                    }
                }
            }
            stage[w][c] = __float2bfloat16(a);
        }
        __syncthreads();
        if (t < 480) {
            int w = t >> 2, part = t & 3;
            size_t pos = ((size_t)b * PH + (h + 1)) * PW + (w + 1);
            char* dstp = (char*)outP + pos * 512 + cbase * 2 + part * 16;
            *(uint4*)dstp = *(const uint4*)&stage[w][part * 8];
        }
        __syncthreads();
    }
}

// Wp[ij][oc][c] = bf16(fuse_w[oc][c][ij])
__global__ void wprep_kernel(const float* __restrict__ fuse_w, __hip_bfloat16* __restrict__ Wp) {
    int i = blockIdx.x * 256 + threadIdx.x;   // exactly 589824
    int ij = i >> 16;
    int oc = (i >> 8) & 255;
    int c  = i & 255;
    Wp[i] = __float2bfloat16(fuse_w[(oc * 256 + c) * 9 + ij]);
}

// Implicit GEMM: res[oc, m] = sum_k Wmat[oc,k] * im2col[k,m] + fuse_b[oc]
// k = ij*256 + c, im2col[m=(b,h,w), k] = outP[b][h+di][w+dj][c]
// Tile 128(oc) x 128(m), BK=64 ch, 4 waves (2x2), reg-staged double-buffered LDS with XOR swizzle.
__global__ __launch_bounds__(256, 2) void gemm_kernel(
        const __hip_bfloat16* __restrict__ outP,
        const __hip_bfloat16* __restrict__ Wp,
        const float* __restrict__ fuse_b,
        float* __restrict__ res) {
    __shared__ __align__(16) char ldsI[2][16384];
    __shared__ __align__(16) char ldsW[2][16384];
    const int t = threadIdx.x;
    const int lane = t & 63;
    const int wv = t >> 6;
    const int wo = wv >> 1;      // oc half
    const int wm = wv & 1;       // m half
    const int bid = blockIdx.x;
    const int bn = bid & 1;      // oc tile (0..1)
    const int bm = bid >> 1;     // m tile (0..899)
    const char* gI = (const char*)outP;
    const char* gW = (const char*)Wp;

    // staging: thread t, chunk q covers bytes lin=(q*256+t)*16 of the 16KB slab
    int srcI[4], srcW[4], dstL[4];
    #pragma unroll
    for (int q = 0; q < 4; ++q) {
        int lin = (q * 256 + t) * 16;
        int p = lin >> 7;            // slab row (m-local or oc-local)
        int rb = lin & 127;          // byte within 64-ch row
        int m = bm * 128 + p;
        int b = m / THW; int r = m - b * THW;
        int h = r / TW;  int w = r - h * TW;
        srcI[q] = (((b * PH + h) * PW + w) << 9) + rb;   // pos*512 + rb
        srcW[q] = ((bn * 128 + p) << 9) + rb;            // oc*512 + rb
        dstL[q] = p * 128 + (rb ^ ((p & 7) << 4));       // XOR-swizzled LDS byte
    }

    // fragment read bases (rows swizzled the same way)
    int aWb[4], aWs[4], aIb[4], aIs[4];
    #pragma unroll
    for (int i = 0; i < 4; ++i) {
        int rw = wo * 64 + i * 16 + (lane & 15);
        aWb[i] = rw * 128; aWs[i] = (rw & 7) << 4;
        int ri = wm * 64 + i * 16 + (lane & 15);
        aIb[i] = ri * 128; aIs[i] = (ri & 7) << 4;
    }
    const int klo = (lane >> 4) << 4;   // byte offset of this lane's 8-elem k group

    f32x4 acc[4][4];
    #pragma unroll
    for (int i = 0; i < 4; ++i) {
        #pragma unroll
        for (int j = 0; j < 4; ++j) {
            f32x4 z = {0.f, 0.f, 0.f, 0.f};
            acc[i][j] = z;
        }
    }

    uint4 vI[4], vW[4];

    auto step_offs = [&](int s, int& offI, int& offW) {
        int ij = s >> 2;
        int c0b = (s & 3) << 7;              // c0 * 2 bytes
        int di = ij / 3, dj = ij - (ij / 3) * 3;
        offI = ((di * PW + dj) << 9) + c0b;
        offW = (ij << 17) + c0b;             // ij * 256 oc * 512B
    };
    auto LOADR = [&](int s) {
        int offI, offW; step_offs(s, offI, offW);
        #pragma unroll
        for (int q = 0; q < 4; ++q) {
            vI[q] = *(const uint4*)(gI + srcI[q] + offI);
            vW[q] = *(const uint4*)(gW + srcW[q] + offW);
        }
    };
    auto WRITEL = [&](int buf) {
        #pragma unroll
        for (int q = 0; q < 4; ++q) {
            *(uint4*)(ldsI[buf] + dstL[q]) = vI[q];
            *(uint4*)(ldsW[buf] + dstL[q]) = vW[q];
        }
    };
    auto COMPUTE = [&](int buf) {
        const char* LI = ldsI[buf];
        const char* LW = ldsW[buf];
        #pragma unroll
        for (int kk = 0; kk < 2; ++kk) {
            int ck = kk * 64 + klo;
            bf16x8 wf[4], iff[4];
            #pragma unroll
            for (int i = 0; i < 4; ++i)
                wf[i] = *(const bf16x8*)(LW + aWb[i] + (ck ^ aWs[i]));
            #pragma unroll
            for (int i = 0; i < 4; ++i)
                iff[i] = *(const bf16x8*)(LI + aIb[i] + (ck ^ aIs[i]));
            #pragma unroll
            for (int o = 0; o < 4; ++o) {
                #pragma unroll
                for (int mi = 0; mi < 4; ++mi)
                    acc[o][mi] = __builtin_amdgcn_mfma_f32_16x16x32_bf16(
                        wf[o], iff[mi], acc[o][mi], 0, 0, 0);
            }
        }
    };

    LOADR(0); WRITEL(0);
    __syncthreads();
    for (int s = 0; s < 36; ++s) {
        int cur = s & 1;
        if (s + 1 < 36) LOADR(s + 1);   // issue-early
        COMPUTE(cur);
        if (s + 1 < 36) WRITEL(cur ^ 1); // write-late
        __syncthreads();
    }

    // epilogue: D row = oc-local, col = m-local; lane: col=lane&15, row=(lane>>4)*4+reg (m89)
    int baseM[4];
    #pragma unroll
    for (int mt = 0; mt < 4; ++mt) {
        int m = bm * 128 + wm * 64 + mt * 16 + (lane & 15);
        int b = m / THW; int r = m - b * THW;
        baseM[mt] = b * (TOC * THW) + r;
    }
    const int ocb0 = bn * 128 + wo * 64 + ((lane >> 4) << 2);
    float bias[4][4];
    #pragma unroll
    for (int o = 0; o < 4; ++o) {
        #pragma unroll
        for (int g = 0; g < 4; ++g)
            bias[o][g] = fuse_b[ocb0 + o * 16 + g];
    }
    #pragma unroll
    for (int o = 0; o < 4; ++o) {
        #pragma unroll
        for (int mt = 0; mt < 4; ++mt) {
            #pragma unroll
            for (int g = 0; g < 4; ++g)
                res[baseM[mt] + (ocb0 + o * 16 + g) * THW] = acc[o][mt][g] + bias[o][g];
        }
    }
}

extern "C" void kernel_launch(void* const* d_in, const int* in_sizes, int n_in,
                              void* d_out, int out_size, void* d_ws, size_t ws_size,
                              hipStream_t stream) {
    const float* x      = (const float*)d_in[0];
    const float* y      = (const float*)d_in[1];
    const float* gen_w  = (const float*)d_in[2];
    const float* gen_b  = (const float*)d_in[3];
    const float* fuse_w = (const float*)d_in[4];
    const float* fuse_b = (const float*)d_in[5];
    float* out = (float*)d_out;
    char* ws = (char*)d_ws;

    __hip_bfloat16* outP = (__hip_bfloat16*)(ws);
    float* yp = (float*)(ws + YP_OFF);
    float* dk = (float*)(ws + DK_OFF);
    __hip_bfloat16* Wp = (__hip_bfloat16*)(ws + WP_OFF);

    zero_kernel<<<2048, 256, 0, stream>>>((uint4*)outP, (int)(OUTP_BYTES / 16));
    pool_kernel<<<TB * TC, 256, 0, stream>>>(y, yp);
    gen_kernel<<<TB, 256, 0, stream>>>(yp, gen_w, gen_b, dk);
    wprep_kernel<<<2304, 256, 0, stream>>>(fuse_w, Wp);
    dw_kernel<<<TB * TH, 1024, 0, stream>>>(x, dk, outP);
    gemm_kernel<<<1800, 256, 0, stream>>>(outP, Wp, fuse_b, out);
}

// Round 2
// 342.217 us; speedup vs baseline: 1.7189x; 1.7189x over previous
//
#include <hip/hip_runtime.h>
#include <hip/hip_bf16.h>
#include <stdint.h>

#define TB 8
#define TC 256
#define TH 120
#define TW 120
#define THW 14400
#define TOC 256
#define PH 122
#define PW 122

typedef short bf16x8 __attribute__((ext_vector_type(8)));
typedef float f32x4 __attribute__((ext_vector_type(4)));

// ---- workspace layout (bytes) ----
#define OUTP_BYTES ((size_t)TB * PH * PW * TC * 2)          // 60,964,864  padded channel-last bf16 intermediate
#define YP_OFF     OUTP_BYTES
#define DK_OFF     (YP_OFF + (size_t)TB * TC * 9 * 4)
#define WP_OFF     (DK_OFF + (size_t)TB * TC * 9 * 4)

__global__ void zero_kernel(uint4* __restrict__ p, int n) {
    int i = blockIdx.x * blockDim.x + threadIdx.x;
    uint4 z; z.x = 0u; z.y = 0u; z.z = 0u; z.w = 0u;
    for (; i < n; i += gridDim.x * blockDim.x) p[i] = z;
}

// yp[b][c][ij] = mean of 40x40 block (ij = bh*3+bw)
__global__ void pool_kernel(const float* __restrict__ y, float* __restrict__ yp) {
    int bc = blockIdx.x;                     // b*256 + c
    const float* src = y + (size_t)bc * THW;
    int t = threadIdx.x;
    float acc[9];
    #pragma unroll
    for (int bin = 0; bin < 9; ++bin) {
        int bh = (bin / 3) * 40, bw = (bin % 3) * 40;
        float a = 0.f;
        for (int i = t; i < 1600; i += 256) {
            int r = i / 40;
            int cw = i - r * 40;
            a += src[(bh + r) * TW + bw + cw];
        }
        acc[bin] = a;
    }
    __shared__ float red[256][9];
    #pragma unroll
    for (int j = 0; j < 9; ++j) red[t][j] = acc[j];
    __syncthreads();
    for (int st = 128; st > 0; st >>= 1) {
        if (t < st) {
            #pragma unroll
            for (int j = 0; j < 9; ++j) red[t][j] += red[t + st][j];
        }
        __syncthreads();
    }
    if (t < 9) yp[bc * 9 + t] = red[0][t] * (1.f / 1600.f);
}

// dk[b][oc][ij] = gen_b[oc] + sum_c gen_w[oc][c] * yp[b][c][ij]
__global__ void gen_kernel(const float* __restrict__ yp, const float* __restrict__ gen_w,
                           const float* __restrict__ gen_b, float* __restrict__ dk) {
    int b = blockIdx.x, t = threadIdx.x;     // t = oc
    __shared__ float yps[TC * 9];
    for (int i = t; i < TC * 9; i += 256) yps[i] = yp[b * TC * 9 + i];
    __syncthreads();
    float acc[9];
    float bias = gen_b[t];
    #pragma unroll
    for (int j = 0; j < 9; ++j) acc[j] = bias;
    for (int c = 0; c < TC; ++c) {
        float w = gen_w[t * TC + c];
        #pragma unroll
        for (int j = 0; j < 9; ++j) acc[j] += w * yps[c * 9 + j];
    }
    #pragma unroll
    for (int j = 0; j < 9; ++j) dk[(b * TC + t) * 9 + j] = acc[j];
}

// depthwise dynamic 3x3 (pad 1, cross-correlation), writes channel-last padded bf16:
// outP[b][h+1][w+1][c]
__global__ __launch_bounds__(1024) void dw_kernel(const float* __restrict__ x,
        const float* __restrict__ dk, __hip_bfloat16* __restrict__ outP) {
    int bid = blockIdx.x;
    int b = bid / TH;
    int h = bid - b * TH;
    int t = threadIdx.x;
    __shared__ float dks[TC * 9];
    __shared__ __align__(16) __hip_bfloat16 stage[TW][40];   // 40 pad keeps 16B-aligned rows
    for (int i = t; i < TC * 9; i += 1024) dks[i] = dk[b * TC * 9 + i];
    __syncthreads();
    const float* xb = x + (size_t)b * TC * THW;
    for (int cc = 0; cc < 8; ++cc) {
        int cbase = cc * 32;
        for (int idx = t; idx < 3840; idx += 1024) {
            int c = idx / TW;
            int w = idx - c * TW;
            const float* xp = xb + (size_t)(cbase + c) * THW;
            const float* dkp = &dks[(cbase + c) * 9];
            float a = 0.f;
            #pragma unroll
            for (int di = 0; di < 3; ++di) {
                int hh = h + di - 1;                 // uniform across block
                if (hh >= 0 && hh < TH) {
                    const float* row = xp + hh * TW;
                    #pragma unroll
                    for (int dj = 0; dj < 3; ++dj) {
                        int ww = w + dj - 1;
                        float xv = (ww >= 0 && ww < TW) ? row[ww] : 0.f;
                        a += xv * dkp[di * 3 + dj];
                    }
                }
            }
            stage[w][c] = __float2bfloat16(a);
        }
        __syncthreads();
        if (t < 480) {
            int w = t >> 2, part = t & 3;
            size_t pos = ((size_t)b * PH + (h + 1)) * PW + (w + 1);
            char* dstp = (char*)outP + pos * 512 + cbase * 2 + part * 16;
            *(uint4*)dstp = *(const uint4*)&stage[w][part * 8];
        }
        __syncthreads();
    }
}

// Wp[ij][oc][c] = bf16(fuse_w[oc][c][ij])
__global__ void wprep_kernel(const float* __restrict__ fuse_w, __hip_bfloat16* __restrict__ Wp) {
    int i = blockIdx.x * 256 + threadIdx.x;   // exactly 589824
    int ij = i >> 16;
    int oc = (i >> 8) & 255;
    int c  = i & 255;
    Wp[i] = __float2bfloat16(fuse_w[(oc * 256 + c) * 9 + ij]);
}

typedef const __attribute__((address_space(1))) char* gas_t;
typedef __attribute__((address_space(3))) char* las_t;
__device__ __forceinline__ void gload16(const char* g, char* l) {
    __builtin_amdgcn_global_load_lds((gas_t)g, (las_t)l, 16, 0, 0);
}

// Implicit GEMM: res[oc, m] = sum_k Wmat[oc,k] * im2col[k,m] + fuse_b[oc]
// k = ij*256 + c, im2col[m=(b,h,w), k] = outP[b][h+di][w+dj][c]
// Tile 128(oc) x 128(m), BK=64, 4 waves (2x2).
// Staging: global_load_lds width=16 into LINEAR LDS, per-lane global source
// pre-swizzled by the inverse of the read-side XOR (rule #21 / m173).
// Pipeline: double-buffer, counted vmcnt(8), raw s_barrier (no vmcnt-0 drain
// in the loop), setprio around MFMA cluster (T4+T5).
__global__ __launch_bounds__(256, 2) void gemm_kernel(
        const __hip_bfloat16* __restrict__ outP,
        const __hip_bfloat16* __restrict__ Wp,
        const float* __restrict__ fuse_b,
        float* __restrict__ res) {
    // lds layout: [buf][I(16K) | W(16K)]
    __shared__ __align__(16) char lds[2][32768];
    const int t = threadIdx.x;
    const int lane = t & 63;
    const int wv = t >> 6;
    const int wo = wv >> 1;      // oc half
    const int wm = wv & 1;       // m half

    // XCD-aware swizzle: 1800 % 8 == 0, each XCD gets a contiguous chunk.
    // Consecutive logical ids alternate oc-halves of the same bm -> the two
    // blocks sharing an I-panel land on the same XCD's L2.
    const int bid0 = blockIdx.x;
    const int logical = (bid0 & 7) * 225 + (bid0 >> 3);
    const int bn = logical & 1;      // oc tile (0..1)
    const int bm = logical >> 1;     // m tile (0..899)

    const char* gI = (const char*)outP;
    const char* gW = (const char*)Wp;

    // ---- staging map (global_load_lds, linear LDS dest) ----
    // segment (q*4 + wv), lane covers LDS bytes ((q*4+wv)*64 + lane)*16.
    // row p = (q*4+wv)*8 + lane/8; byte-in-row rb = (lane&7)*16.
    // source byte-in-row rb' = rb ^ ((p&7)<<4)  (p&7 == lane>>3 here).
    const int rbp = (((lane & 7) ^ (lane >> 3)) << 4);   // pre-swizzled source byte
    int srcI[4], srcW[4];
    #pragma unroll
    for (int q = 0; q < 4; ++q) {
        int p = (q * 4 + wv) * 8 + (lane >> 3);
        int m = bm * 128 + p;
        int b = m / THW; int r = m - b * THW;
        int h = r / TW;  int w = r - h * TW;
        srcI[q] = (((b * PH + h) * PW + w) << 9) + rbp;  // pos*512 + rb'
        srcW[q] = ((bn * 128 + p) << 9) + rbp;           // oc*512 + rb'
    }
    const int segBase = wv * 1024;   // + q*4096 per chunk (wave-uniform)

    // ---- fragment read bases (read-side XOR swizzle, same as R0-verified) ----
    int aWb[4], aWs[4], aIb[4], aIs[4];
    #pragma unroll
    for (int i = 0; i < 4; ++i) {
        int rw = wo * 64 + i * 16 + (lane & 15);
        aWb[i] = rw * 128; aWs[i] = (rw & 7) << 4;
        int ri = wm * 64 + i * 16 + (lane & 15);
        aIb[i] = ri * 128; aIs[i] = (ri & 7) << 4;
    }
    const int klo = (lane >> 4) << 4;   // byte offset of this lane's 8-elem k group

    f32x4 acc[4][4];
    #pragma unroll
    for (int i = 0; i < 4; ++i) {
        #pragma unroll
        for (int j = 0; j < 4; ++j) {
            f32x4 z = {0.f, 0.f, 0.f, 0.f};
            acc[i][j] = z;
        }
    }

    auto step_offs = [&](int s, int& offI, int& offW) {
        int ij = s >> 2;
        int c0b = (s & 3) << 7;              // c0 * 2 bytes
        int di = ij / 3, dj = ij - (ij / 3) * 3;
        offI = ((di * PW + dj) << 9) + c0b;
        offW = (ij << 17) + c0b;             // ij * 256 oc * 512B
    };
    auto STAGE = [&](int buf, int s) {
        int offI, offW; step_offs(s, offI, offW);
        char* LI = &lds[buf][0];
        char* LW = &lds[buf][16384];
        #pragma unroll
        for (int q = 0; q < 4; ++q) {
            gload16(gI + srcI[q] + offI, LI + segBase + q * 4096);
            gload16(gW + srcW[q] + offW, LW + segBase + q * 4096);
        }
    };
    auto COMPUTE = [&](int buf) {
        const char* LI = &lds[buf][0];
        const char* LW = &lds[buf][16384];
        #pragma unroll
        for (int kk = 0; kk < 2; ++kk) {
            int ck = kk * 64 + klo;
            bf16x8 wf[4], iff[4];
            #pragma unroll
            for (int i = 0; i < 4; ++i)
                wf[i] = *(const bf16x8*)(LW + aWb[i] + (ck ^ aWs[i]));
            #pragma unroll
            for (int i = 0; i < 4; ++i)
                iff[i] = *(const bf16x8*)(LI + aIb[i] + (ck ^ aIs[i]));
            __builtin_amdgcn_s_setprio(1);
            #pragma unroll
            for (int o = 0; o < 4; ++o) {
                #pragma unroll
                for (int mi = 0; mi < 4; ++mi)
                    acc[o][mi] = __builtin_amdgcn_mfma_f32_16x16x32_bf16(
                        wf[o], iff[mi], acc[o][mi], 0, 0, 0);
            }
            __builtin_amdgcn_s_setprio(0);
        }
    };

    STAGE(0, 0);
    #pragma unroll 1
    for (int s = 0; s < 35; ++s) {
        int cur = s & 1;
        STAGE(cur ^ 1, s + 1);                       // 8 more loads in flight
        asm volatile("s_waitcnt vmcnt(8)" ::: "memory");  // wait only cur's 8
        __builtin_amdgcn_s_barrier();
        asm volatile("" ::: "memory");
        COMPUTE(cur);
        asm volatile("" ::: "memory");
        __builtin_amdgcn_s_barrier();                // all done reading buf[cur]
        asm volatile("" ::: "memory");
    }
    asm volatile("s_waitcnt vmcnt(0)" ::: "memory");
    __builtin_amdgcn_s_barrier();
    asm volatile("" ::: "memory");
    COMPUTE(1);                                      // s = 35

    // epilogue: D row = oc-local, col = m-local; lane: col=lane&15, row=(lane>>4)*4+reg (m89)
    int baseM[4];
    #pragma unroll
    for (int mt = 0; mt < 4; ++mt) {
        int m = bm * 128 + wm * 64 + mt * 16 + (lane & 15);
        int b = m / THW; int r = m - b * THW;
        baseM[mt] = b * (TOC * THW) + r;
    }
    const int ocb0 = bn * 128 + wo * 64 + ((lane >> 4) << 2);
    float bias[4][4];
    #pragma unroll
    for (int o = 0; o < 4; ++o) {
        #pragma unroll
        for (int g = 0; g < 4; ++g)
            bias[o][g] = fuse_b[ocb0 + o * 16 + g];
    }
    #pragma unroll
    for (int o = 0; o < 4; ++o) {
        #pragma unroll
        for (int mt = 0; mt < 4; ++mt) {
            #pragma unroll
            for (int g = 0; g < 4; ++g)
                res[baseM[mt] + (ocb0 + o * 16 + g) * THW] = acc[o][mt][g] + bias[o][g];
        }
    }
}

extern "C" void kernel_launch(void* const* d_in, const int* in_sizes, int n_in,
                              void* d_out, int out_size, void* d_ws, size_t ws_size,
                              hipStream_t stream) {
    const float* x      = (const float*)d_in[0];
    const float* y      = (const float*)d_in[1];
    const float* gen_w  = (const float*)d_in[2];
    const float* gen_b  = (const float*)d_in[3];
    const float* fuse_w = (const float*)d_in[4];
    const float* fuse_b = (const float*)d_in[5];
    float* out = (float*)d_out;
    char* ws = (char*)d_ws;

    __hip_bfloat16* outP = (__hip_bfloat16*)(ws);
    float* yp = (float*)(ws + YP_OFF);
    float* dk = (float*)(ws + DK_OFF);
    __hip_bfloat16* Wp = (__hip_bfloat16*)(ws + WP_OFF);

    zero_kernel<<<2048, 256, 0, stream>>>((uint4*)outP, (int)(OUTP_BYTES / 16));
    pool_kernel<<<TB * TC, 256, 0, stream>>>(y, yp);
    gen_kernel<<<TB, 256, 0, stream>>>(yp, gen_w, gen_b, dk);
    wprep_kernel<<<2304, 256, 0, stream>>>(fuse_w, Wp);
    dw_kernel<<<TB * TH, 1024, 0, stream>>>(x, dk, outP);
    gemm_kernel<<<1800, 256, 0, stream>>>(outP, Wp, fuse_b, out);
}

// Round 3
// 243.664 us; speedup vs baseline: 2.4142x; 1.4045x over previous
//
#include <hip/hip_runtime.h>
#include <hip/hip_bf16.h>
#include <stdint.h>

#define TB 8
#define TC 256
#define TH 120
#define TW 120
#define THW 14400
#define TOC 256
#define PH 122
#define PW 122

typedef short bf16x8 __attribute__((ext_vector_type(8)));
typedef float f32x4 __attribute__((ext_vector_type(4)));

// ---- workspace layout (bytes) ----
#define OUTP_BYTES ((size_t)TB * PH * PW * TC * 2)          // 60,964,864  padded channel-last bf16 intermediate
#define YP_OFF     OUTP_BYTES
#define DK_OFF     (YP_OFF + (size_t)TB * TC * 9 * 4)
#define WP_OFF     (DK_OFF + (size_t)TB * TC * 9 * 4)

// Zero only the 1-wide halo ring of outP (interior is fully written by dw).
// positions per b: h=0 row (122) + h=121 row (122) + 120*(w=0,121) = 484.
// total 8*484 = 3872 positions * 512B; 32 threads of 16B per position.
__global__ void zero_halo_kernel(char* __restrict__ outP) {
    int i = blockIdx.x * 256 + threadIdx.x;      // 484 blocks * 256 = 123904 exactly
    int pos_idx = i >> 5, part = i & 31;
    int b = pos_idx / 484; int k = pos_idx - b * 484;
    int h, w;
    if (k < 122)      { h = 0;   w = k; }
    else if (k < 244) { h = 121; w = k - 122; }
    else { int m = k - 244; h = 1 + (m >> 1); w = (m & 1) ? 121 : 0; }
    size_t pos = ((size_t)b * PH + h) * PW + w;
    uint4 z; z.x = 0u; z.y = 0u; z.z = 0u; z.w = 0u;
    *(uint4*)(outP + pos * 512 + part * 16) = z;
}

// yp[b][c][ij] = mean of 40x40 block (ij = bh*3+bw)
// lane t<120 streams row t via float4; two-stage LDS reduce.
__global__ __launch_bounds__(128) void pool_kernel(const float* __restrict__ y,
                                                   float* __restrict__ yp) {
    int bc = blockIdx.x, t = threadIdx.x;
    __shared__ float pr[120][4];
    __shared__ float p2[9][8];
    const float* src = y + (size_t)bc * THW;
    if (t < 120) {
        const float4* row = (const float4*)(src + t * TW);
        float s0 = 0.f, s1 = 0.f, s2 = 0.f;
        #pragma unroll
        for (int j = 0; j < 10; ++j)  { float4 v = row[j]; s0 += (v.x + v.y) + (v.z + v.w); }
        #pragma unroll
        for (int j = 10; j < 20; ++j) { float4 v = row[j]; s1 += (v.x + v.y) + (v.z + v.w); }
        #pragma unroll
        for (int j = 20; j < 30; ++j) { float4 v = row[j]; s2 += (v.x + v.y) + (v.z + v.w); }
        pr[t][0] = s0; pr[t][1] = s1; pr[t][2] = s2;
    }
    __syncthreads();
    if (t < 72) {
        int bin = t >> 3, ch = t & 7;
        int bh = bin / 3, bw = bin - bh * 3;
        float a = 0.f;
        #pragma unroll
        for (int r = 0; r < 5; ++r) a += pr[bh * 40 + ch * 5 + r][bw];
        p2[bin][ch] = a;
    }
    __syncthreads();
    if (t < 9) {
        float a = 0.f;
        #pragma unroll
        for (int j = 0; j < 8; ++j) a += p2[t][j];
        yp[bc * 9 + t] = a * (1.f / 1600.f);
    }
}

// dk[b][oc][ij] = gen_b[oc] + sum_c gen_w[oc][c] * yp[b][c][ij]
__global__ void gen_kernel(const float* __restrict__ yp, const float* __restrict__ gen_w,
                           const float* __restrict__ gen_b, float* __restrict__ dk) {
    int b = blockIdx.x, t = threadIdx.x;     // t = oc
    __shared__ float yps[TC * 9];
    for (int i = t; i < TC * 9; i += 256) yps[i] = yp[b * TC * 9 + i];
    __syncthreads();
    float acc[9];
    float bias = gen_b[t];
    #pragma unroll
    for (int j = 0; j < 9; ++j) acc[j] = bias;
    for (int c = 0; c < TC; ++c) {
        float w = gen_w[t * TC + c];
        #pragma unroll
        for (int j = 0; j < 9; ++j) acc[j] += w * yps[c * 9 + j];
    }
    #pragma unroll
    for (int j = 0; j < 9; ++j) dk[(b * TC + t) * 9 + j] = acc[j];
}

// depthwise dynamic 3x3 (pad 1, cross-correlation) -> channel-last padded bf16
// outP[b][h+1][w+1][c].  Grid: (b, cc, hs) = 8*8*8 = 512 blocks, 1024 threads.
// thread = (c = t>>5 in [0,32), wq = t&31, active wq<30) owns w = 4*wq..4*wq+3
// across a 15-row strip; rows h-1,h,h+1 rolled in registers.
__global__ __launch_bounds__(1024) void dw_kernel(const float* __restrict__ x,
        const float* __restrict__ dk, __hip_bfloat16* __restrict__ outP) {
    int bid = blockIdx.x;
    int hs = bid & 7;
    int cc = (bid >> 3) & 7;
    int b  = bid >> 6;
    int t = threadIdx.x;
    int c  = t >> 5;
    int wq = t & 31;
    bool active = wq < 30;
    int w0 = wq * 4;
    int cg = cc * 32 + c;
    const float* xp = x + (size_t)(b * TC + cg) * THW;
    const float* dkp = dk + (size_t)(b * TC + cg) * 9;
    float k0[3], k1[3], k2[3];
    #pragma unroll
    for (int j = 0; j < 3; ++j) { k0[j] = dkp[j]; k1[j] = dkp[3 + j]; k2[j] = dkp[6 + j]; }

    __shared__ __align__(16) __hip_bfloat16 stage[2][32][124];

    int h0 = hs * 15;
    float A[6], B[6], C[6];
    auto loadrow = [&](int hh, float* V) {
        if (hh < 0 || hh >= TH) {
            #pragma unroll
            for (int j = 0; j < 6; ++j) V[j] = 0.f;
            return;
        }
        const float* row = xp + hh * TW;
        float4 v = *(const float4*)(row + w0);
        V[1] = v.x; V[2] = v.y; V[3] = v.z; V[4] = v.w;
        V[0] = (wq > 0)  ? row[w0 - 1] : 0.f;
        V[5] = (wq < 29) ? row[w0 + 4] : 0.f;
    };
    if (active) { loadrow(h0 - 1, A); loadrow(h0, B); }

    for (int r = 0; r < 15; ++r) {
        int h = h0 + r;
        if (active) {
            loadrow(h + 1, C);
            ushort4 pk;
            #pragma unroll
            for (int i = 0; i < 4; ++i) {
                float o = A[i] * k0[0] + A[i + 1] * k0[1] + A[i + 2] * k0[2]
                        + B[i] * k1[0] + B[i + 1] * k1[1] + B[i + 2] * k1[2]
                        + C[i] * k2[0] + C[i + 1] * k2[1] + C[i + 2] * k2[2];
                __hip_bfloat16 hb = __float2bfloat16(o);
                ushort u = *(ushort*)&hb;
                if (i == 0) pk.x = u; else if (i == 1) pk.y = u;
                else if (i == 2) pk.z = u; else pk.w = u;
            }
            *(ushort4*)&stage[r & 1][c][w0] = pk;
            #pragma unroll
            for (int j = 0; j < 6; ++j) { A[j] = B[j]; B[j] = C[j]; }
        }
        __syncthreads();
        if (t < 480) {
            int w = t >> 2, part = t & 3;
            ushort vals[8];
            #pragma unroll
            for (int j = 0; j < 8; ++j) vals[j] = *(const ushort*)&stage[r & 1][part * 8 + j][w];
            uint4 o;
            o.x = (uint)vals[0] | ((uint)vals[1] << 16);
            o.y = (uint)vals[2] | ((uint)vals[3] << 16);
            o.z = (uint)vals[4] | ((uint)vals[5] << 16);
            o.w = (uint)vals[6] | ((uint)vals[7] << 16);
            size_t pos = ((size_t)b * PH + (h + 1)) * PW + (w + 1);
            *(uint4*)((char*)outP + pos * 512 + cc * 64 + part * 16) = o;
        }
    }
}

// Wp[ij][oc][c] = bf16(fuse_w[oc][c][ij])
__global__ void wprep_kernel(const float* __restrict__ fuse_w, __hip_bfloat16* __restrict__ Wp) {
    int i = blockIdx.x * 256 + threadIdx.x;   // exactly 589824
    int ij = i >> 16;
    int oc = (i >> 8) & 255;
    int c  = i & 255;
    Wp[i] = __float2bfloat16(fuse_w[(oc * 256 + c) * 9 + ij]);
}

typedef const __attribute__((address_space(1))) char* gas_t;
typedef __attribute__((address_space(3))) char* las_t;
__device__ __forceinline__ void gload16(const char* g, char* l) {
    __builtin_amdgcn_global_load_lds((gas_t)g, (las_t)l, 16, 0, 0);
}

// Implicit GEMM: res[oc, m] = sum_k Wmat[oc,k] * im2col[k,m] + fuse_b[oc]
// (unchanged from R1: global_load_lds w=16, pre-swizzled source, linear LDS,
// double-buffer, counted vmcnt(8), raw barriers, setprio, XCD swizzle)
__global__ __launch_bounds__(256, 2) void gemm_kernel(
        const __hip_bfloat16* __restrict__ outP,
        const __hip_bfloat16* __restrict__ Wp,
        const float* __restrict__ fuse_b,
        float* __restrict__ res) {
    __shared__ __align__(16) char lds[2][32768];
    const int t = threadIdx.x;
    const int lane = t & 63;
    const int wv = t >> 6;
    const int wo = wv >> 1;      // oc half
    const int wm = wv & 1;       // m half

    const int bid0 = blockIdx.x;
    const int logical = (bid0 & 7) * 225 + (bid0 >> 3);
    const int bn = logical & 1;      // oc tile (0..1)
    const int bm = logical >> 1;     // m tile (0..899)

    const char* gI = (const char*)outP;
    const char* gW = (const char*)Wp;

    const int rbp = (((lane & 7) ^ (lane >> 3)) << 4);   // pre-swizzled source byte
    int srcI[4], srcW[4];
    #pragma unroll
    for (int q = 0; q < 4; ++q) {
        int p = (q * 4 + wv) * 8 + (lane >> 3);
        int m = bm * 128 + p;
        int b = m / THW; int r = m - b * THW;
        int h = r / TW;  int w = r - h * TW;
        srcI[q] = (((b * PH + h) * PW + w) << 9) + rbp;  // pos*512 + rb'
        srcW[q] = ((bn * 128 + p) << 9) + rbp;           // oc*512 + rb'
    }
    const int segBase = wv * 1024;   // + q*4096 per chunk (wave-uniform)

    int aWb[4], aWs[4], aIb[4], aIs[4];
    #pragma unroll
    for (int i = 0; i < 4; ++i) {
        int rw = wo * 64 + i * 16 + (lane & 15);
        aWb[i] = rw * 128; aWs[i] = (rw & 7) << 4;
        int ri = wm * 64 + i * 16 + (lane & 15);
        aIb[i] = ri * 128; aIs[i] = (ri & 7) << 4;
    }
    const int klo = (lane >> 4) << 4;

    f32x4 acc[4][4];
    #pragma unroll
    for (int i = 0; i < 4; ++i) {
        #pragma unroll
        for (int j = 0; j < 4; ++j) {
            f32x4 z = {0.f, 0.f, 0.f, 0.f};
            acc[i][j] = z;
        }
    }

    auto step_offs = [&](int s, int& offI, int& offW) {
        int ij = s >> 2;
        int c0b = (s & 3) << 7;
        int di = ij / 3, dj = ij - (ij / 3) * 3;
        offI = ((di * PW + dj) << 9) + c0b;
        offW = (ij << 17) + c0b;
    };
    auto STAGE = [&](int buf, int s) {
        int offI, offW; step_offs(s, offI, offW);
        char* LI = &lds[buf][0];
        char* LW = &lds[buf][16384];
        #pragma unroll
        for (int q = 0; q < 4; ++q) {
            gload16(gI + srcI[q] + offI, LI + segBase + q * 4096);
            gload16(gW + srcW[q] + offW, LW + segBase + q * 4096);
        }
    };
    auto COMPUTE = [&](int buf) {
        const char* LI = &lds[buf][0];
        const char* LW = &lds[buf][16384];
        #pragma unroll
        for (int kk = 0; kk < 2; ++kk) {
            int ck = kk * 64 + klo;
            bf16x8 wf[4], iff[4];
            #pragma unroll
            for (int i = 0; i < 4; ++i)
                wf[i] = *(const bf16x8*)(LW + aWb[i] + (ck ^ aWs[i]));
            #pragma unroll
            for (int i = 0; i < 4; ++i)
                iff[i] = *(const bf16x8*)(LI + aIb[i] + (ck ^ aIs[i]));
            __builtin_amdgcn_s_setprio(1);
            #pragma unroll
            for (int o = 0; o < 4; ++o) {
                #pragma unroll
                for (int mi = 0; mi < 4; ++mi)
                    acc[o][mi] = __builtin_amdgcn_mfma_f32_16x16x32_bf16(
                        wf[o], iff[mi], acc[o][mi], 0, 0, 0);
            }
            __builtin_amdgcn_s_setprio(0);
        }
    };

    STAGE(0, 0);
    #pragma unroll 1
    for (int s = 0; s < 35; ++s) {
        int cur = s & 1;
        STAGE(cur ^ 1, s + 1);
        asm volatile("s_waitcnt vmcnt(8)" ::: "memory");
        __builtin_amdgcn_s_barrier();
        asm volatile("" ::: "memory");
        COMPUTE(cur);
        asm volatile("" ::: "memory");
        __builtin_amdgcn_s_barrier();
        asm volatile("" ::: "memory");
    }
    asm volatile("s_waitcnt vmcnt(0)" ::: "memory");
    __builtin_amdgcn_s_barrier();
    asm volatile("" ::: "memory");
    COMPUTE(1);

    int baseM[4];
    #pragma unroll
    for (int mt = 0; mt < 4; ++mt) {
        int m = bm * 128 + wm * 64 + mt * 16 + (lane & 15);
        int b = m / THW; int r = m - b * THW;
        baseM[mt] = b * (TOC * THW) + r;
    }
    const int ocb0 = bn * 128 + wo * 64 + ((lane >> 4) << 2);
    float bias[4][4];
    #pragma unroll
    for (int o = 0; o < 4; ++o) {
        #pragma unroll
        for (int g = 0; g < 4; ++g)
            bias[o][g] = fuse_b[ocb0 + o * 16 + g];
    }
    #pragma unroll
    for (int o = 0; o < 4; ++o) {
        #pragma unroll
        for (int mt = 0; mt < 4; ++mt) {
            #pragma unroll
            for (int g = 0; g < 4; ++g)
                res[baseM[mt] + (ocb0 + o * 16 + g) * THW] = acc[o][mt][g] + bias[o][g];
        }
    }
}

extern "C" void kernel_launch(void* const* d_in, const int* in_sizes, int n_in,
                              void* d_out, int out_size, void* d_ws, size_t ws_size,
                              hipStream_t stream) {
    const float* x      = (const float*)d_in[0];
    const float* y      = (const float*)d_in[1];
    const float* gen_w  = (const float*)d_in[2];
    const float* gen_b  = (const float*)d_in[3];
    const float* fuse_w = (const float*)d_in[4];
    const float* fuse_b = (const float*)d_in[5];
    float* out = (float*)d_out;
    char* ws = (char*)d_ws;

    __hip_bfloat16* outP = (__hip_bfloat16*)(ws);
    float* yp = (float*)(ws + YP_OFF);
    float* dk = (float*)(ws + DK_OFF);
    __hip_bfloat16* Wp = (__hip_bfloat16*)(ws + WP_OFF);

    zero_halo_kernel<<<484, 256, 0, stream>>>((char*)outP);
    pool_kernel<<<TB * TC, 128, 0, stream>>>(y, yp);
    gen_kernel<<<TB, 256, 0, stream>>>(yp, gen_w, gen_b, dk);
    wprep_kernel<<<2304, 256, 0, stream>>>(fuse_w, Wp);
    dw_kernel<<<512, 1024, 0, stream>>>(x, dk, outP);
    gemm_kernel<<<1800, 256, 0, stream>>>(outP, Wp, fuse_b, out);
}